// Round 1
// baseline (17374.994 us; speedup 1.0000x reference)
//
#include <hip/hip_runtime.h>
#include <hip/hip_bf16.h>
#include <math.h>

// DARQN: conv×3 -> per-step additive attention + LSTM scan (T=2048) -> q head.
// R3: scan comm rebuilt around seq-embedded 8-byte atomic words.
//  - h broadcast: u64 = (seq<<32)|f32bits, per-thread poll of own dim (1 RT, no
//    flag, no release fence, no drain barriers).
//  - ctx partials: u64 = (seq<<32)|(2×bf16), 32-load gather issued BEFORE the
//    h@Whh MFMA chain (round-0 RT hidden under MFMAs); own-WG partial served
//    from LDS (cpl) so round-0 only needs the 7 remote WGs.
//  - barriers per step: 8 -> 6 (B0/B8 gone, B6 now cheap LDS-publish barrier).
//  - rcp-based tanh/sigmoid/softmax-inv (v_rcp_f32 instead of full-precision
//    divide sequences on the serial path).
//  - grid=57, workers = blockIdx%8==0: round-robin block->XCD heuristic puts
//    all 8 workers on one XCD (correctness does not depend on the mapping).

#define T_FRAMES 2048
#define NI 49
#define HID 256
#define NA 18
#define NWG 8

typedef __bf16 v8bf __attribute__((ext_vector_type(8)));
typedef float v4f __attribute__((ext_vector_type(4)));

// ---------------- workspace layout (bytes) ----------------
static constexpr size_t OFF_FM1   = 0;                  // fm1 [2048,32,20,20] f32; reused for A [2048,49,256] f32
static constexpr size_t OFF_FM2   = 104857600;          // fm2 [2048,64,9,9] f32; reused for comm block
static constexpr size_t OFF_VECS  = 147324928;          // vecs [2048,49,256] f32
static constexpr size_t OFF_W2B   = 250085376;          // bf16 256*256
static constexpr size_t OFF_WIHB  = OFF_W2B  + 131072;  // bf16 1024*256
static constexpr size_t OFF_WHHB  = OFF_WIHB + 524288;  // bf16 1024*256
static constexpr size_t OFF_W1T   = OFF_WHHB + 524288;  // f32 256*256
// comm block aliases fm2 region (valid after conv3 consumed fm2):
static constexpr size_t OFF_HBUF  = OFF_FM2;            // u64[256]  (seq|f32)
static constexpr size_t OFF_CPUB  = OFF_FM2 + 2048;     // u64[8*128] (seq | 2×bf16)

// ---------------- weight prep ----------------
__global__ void prep_weights(const float* __restrict__ w2, const float* __restrict__ wih,
                             const float* __restrict__ whh, const float* __restrict__ w1,
                             __bf16* w2b, __bf16* wihb, __bf16* whhb, float* w1t) {
  int idx = blockIdx.x * 256 + threadIdx.x;
  int stride = gridDim.x * 256;
  for (int i = idx; i < 65536; i += stride) w2b[i] = (__bf16)w2[i];
  for (int i = idx; i < 262144; i += stride) wihb[i] = (__bf16)wih[i];
  for (int i = idx; i < 262144; i += stride) whhb[i] = (__bf16)whh[i];
  for (int i = idx; i < 65536; i += stride) {
    int r = i >> 8, c = i & 255;
    w1t[c * 256 + r] = w1[i];
  }
}

// ---------------- conv1: [T,1,84,84] -> [T,32,20,20], k8 s4 ----------------
__global__ void conv1_k(const float* __restrict__ x, const float* __restrict__ w,
                        const float* __restrict__ b, float* __restrict__ y) {
  int idx = blockIdx.x * 256 + threadIdx.x;
  if (idx >= T_FRAMES * 32 * 20 * 20) return;
  int xx = idx % 20, yy = (idx / 20) % 20, o = (idx / 400) % 32, t = idx / 12800;
  const float* xp = x + t * 7056 + yy * 4 * 84 + xx * 4;
  const float* wp = w + o * 64;
  float acc = b[o];
  #pragma unroll
  for (int ky = 0; ky < 8; ky++)
    #pragma unroll
    for (int kx = 0; kx < 8; kx++)
      acc += xp[ky * 84 + kx] * wp[ky * 8 + kx];
  y[idx] = fmaxf(acc, 0.f);
}

// ---------------- conv2: [T,32,20,20] -> [T,64,9,9], k4 s2 ----------------
__global__ __launch_bounds__(256) void conv2_k(const float* __restrict__ fm1, const float* __restrict__ w,
                                               const float* __restrict__ b, float* __restrict__ fm2) {
  __shared__ float xs[32 * 400];
  int t = blockIdx.x, tid = threadIdx.x;
  for (int i = tid; i < 12800; i += 256) xs[i] = fm1[t * 12800 + i];
  __syncthreads();
  int o = tid >> 2, q = tid & 3;
  int p0 = q * 21, p1 = (p0 + 21 < 81) ? p0 + 21 : 81;
  int ob[21];
  #pragma unroll
  for (int i2 = 0; i2 < 21; i2++) {
    int p = p0 + i2; if (p > 80) p = 80;
    int yy = p / 9, xx2 = p - yy * 9;
    ob[i2] = yy * 40 + xx2 * 2;
  }
  float acc[21];
  #pragma unroll
  for (int i2 = 0; i2 < 21; i2++) acc[i2] = 0.f;
  for (int c = 0; c < 32; c++) {
    int cbase = c * 400;
    for (int ky = 0; ky < 4; ky++)
      for (int kx = 0; kx < 4; kx++) {
        float wgt = w[((o * 32 + c) * 4 + ky) * 4 + kx];
        int kyo = ky * 20 + kx;
        #pragma unroll
        for (int i2 = 0; i2 < 21; i2++)
          acc[i2] += wgt * xs[cbase + ob[i2] + kyo];
      }
  }
  float bo = b[o];
  #pragma unroll
  for (int i2 = 0; i2 < 21; i2++) {
    int p = p0 + i2;
    if (p < p1) fm2[t * 5184 + o * 81 + p] = fmaxf(acc[i2] + bo, 0.f);
  }
}

// ---------------- conv3: [T,64,9,9] -> vecs [T,49,256], k3 s1 ----------------
__global__ __launch_bounds__(256) void conv3_k(const float* __restrict__ fm2, const float* __restrict__ w,
                                               const float* __restrict__ b, float* __restrict__ vecs) {
  __shared__ float xs[64 * 81];
  __shared__ float ws4[256][37];
  int t = blockIdx.x, tid = threadIdx.x;
  for (int i = tid; i < 64 * 81; i += 256) xs[i] = fm2[t * 5184 + i];
  float acc[49];
  #pragma unroll
  for (int i = 0; i < 49; i++) acc[i] = 0.f;
  for (int c0 = 0; c0 < 64; c0 += 4) {
    __syncthreads();
    for (int i = tid; i < 256 * 36; i += 256) {
      int oo = i / 36, j = i - oo * 36;
      ws4[oo][j] = w[oo * 576 + c0 * 9 + j];
    }
    __syncthreads();
    for (int cc = 0; cc < 4; cc++)
      for (int ky = 0; ky < 3; ky++)
        for (int kx = 0; kx < 3; kx++) {
          float wgt = ws4[tid][cc * 9 + ky * 3 + kx];
          const float* xp = &xs[(c0 + cc) * 81 + ky * 9 + kx];
          #pragma unroll
          for (int yy = 0; yy < 7; yy++)
            #pragma unroll
            for (int xx = 0; xx < 7; xx++)
              acc[yy * 7 + xx] += wgt * xp[yy * 9 + xx];
        }
  }
  float bo = b[tid];
  for (int i = 0; i < 49; i++)
    vecs[(t * 49 + i) * 256 + tid] = fmaxf(acc[i] + bo, 0.f);
}

// ---------------- A[t,i,:] = vecs[t,i,:] @ W1^T + b1 ----------------
__global__ __launch_bounds__(256) void aprep_k(const float* __restrict__ vecs, const float* __restrict__ w1t,
                                               const float* __restrict__ b1, float* __restrict__ A) {
  __shared__ float vs[49][256];
  int t = blockIdx.x, tid = threadIdx.x;
  for (int i = tid; i < 49 * 256; i += 256) vs[i >> 8][i & 255] = vecs[t * 12544 + i];
  __syncthreads();
  float acc[49];
  #pragma unroll
  for (int i = 0; i < 49; i++) acc[i] = 0.f;
  for (int k = 0; k < 256; k++) {
    float wgt = w1t[k * 256 + tid];
    #pragma unroll
    for (int i = 0; i < 49; i++) acc[i] += vs[i][k] * wgt;
  }
  float bb = b1[tid];
  for (int i = 0; i < 49; i++) A[(t * 49 + i) * 256 + tid] = acc[i] + bb;
}

// ---------------- init comm words (after conv3: aliases fm2) ----------------
__global__ void init_comm(unsigned long long* hbuf, unsigned long long* cpub) {
  int idx = blockIdx.x * 256 + threadIdx.x;
  if (idx < 256) hbuf[idx] = 0ull;
  if (idx < NWG * 128) cpub[idx] = 0ull;
}

__device__ __forceinline__ float tanh_fast(float x) {
  float e = __expf(2.f * x);
  return 1.f - 2.f * __builtin_amdgcn_rcpf(e + 1.f);
}
__device__ __forceinline__ float sigm_fast(float x) {
  return __builtin_amdgcn_rcpf(1.f + __expf(-x));
}

// ---------------- sequential scan: 8 persistent WGs, seq-embedded u64 comm ----------------
__global__ __launch_bounds__(256, 1) void scan_k(
    const float* __restrict__ A, const float* __restrict__ vecs,
    const __bf16* __restrict__ w2b, const __bf16* __restrict__ wihb, const __bf16* __restrict__ whhb,
    const float* __restrict__ b2g, const float* __restrict__ bihg, const float* __restrict__ bhhg,
    const float* __restrict__ qw, const float* __restrict__ qb,
    unsigned long long* hbuf, unsigned long long* cpub, float* out) {
  if (blockIdx.x & 7) return;          // XCD-colocation heuristic (see header)
  const int w = blockIdx.x >> 3;       // worker 0..7

  __shared__ __bf16 Ss[16][264];   // row byte-stride 528 (16B-aligned)
  __shared__ float hs[HID];
  __shared__ __bf16 hbf[HID];
  __shared__ float Wt[8][HID];     // logits / softmax rows
  __shared__ float cxp[8][HID];    // per-row ctx products
  __shared__ float b2s[HID];
  __shared__ float gb[4][32];
  __shared__ unsigned cpl[128];    // own-WG ctx partial (packed bf16 pairs)

  const int tid = threadIdx.x;
  const int lane = tid & 63;
  const int wv = tid >> 6;          // wave 0..3 (= LSTM gate id)
  const int quad = lane >> 4;
  const int l15 = lane & 15;
  const int r0 = 6 * w;                       // attention rows [r0, r0+nr)
  const int nr = (w < 7) ? 6 : 7;             // 7*6 + 7 = 49
  const int prow = tid >> 5;        // 0..7: staging row
  const int pcol = (tid & 31) * 8;  // 8 contiguous cols

  for (int i = tid; i < 16 * 264; i += 256) (&Ss[0][0])[i] = (__bf16)0.f;
  for (int i = tid; i < 8 * HID; i += 256) (&cxp[0][0])[i] = 0.f;
  b2s[tid] = b2g[tid];
  hs[tid] = 0.f;
  hbf[tid] = (__bf16)0.f;
  float cbias[4];
  if (tid < 32) {
    #pragma unroll
    for (int g = 0; g < 4; g++) {
      int row = 256 * g + 32 * w + tid;
      cbias[g] = bihg[row] + bhhg[row];
    }
  }
  float creg = 0.f;  // cell state, tid<32 owns dim 32*w+tid

  // ---- register-resident MFMA B-fragments ----
  v8bf BW2[4][8];  // attention: wave wv owns logit cols wv*64 + ntl*16 + l15
  #pragma unroll
  for (int ntl = 0; ntl < 4; ntl++) {
    const int row = wv * 64 + ntl * 16 + l15;
    #pragma unroll
    for (int k = 0; k < 8; k++)
      BW2[ntl][k] = *(const v8bf*)(w2b + row * 256 + k * 32 + quad * 8);
  }
  v8bf BIH[2][8], BHH[2][8];  // LSTM: gate wv, dims 32*w + nt*16 + l15
  #pragma unroll
  for (int nt = 0; nt < 2; nt++) {
    const int row = 256 * wv + 32 * w + nt * 16 + l15;
    #pragma unroll
    for (int k = 0; k < 8; k++) {
      BIH[nt][k] = *(const v8bf*)(wihb + row * 256 + k * 32 + quad * 8);
      BHH[nt][k] = *(const v8bf*)(whhb + row * 256 + k * 32 + quad * 8);
    }
  }
  __syncthreads();

  for (int t = 0; t < T_FRAMES; t++) {
    // issue this step's A/vecs loads (fly during the h wait)
    int rr = r0 + prow; if (rr > 48) rr = 48;
    const float* Ap = A + ((long)t * NI + rr) * HID + pcol;
    const float* Vp = vecs + ((long)t * NI + rr) * HID + pcol;
    const float4 a40 = *(const float4*)(Ap);
    const float4 a41 = *(const float4*)(Ap + 4);
    const float4 v40 = *(const float4*)(Vp);
    const float4 v41 = *(const float4*)(Vp + 4);

    if (t > 0) {  // per-thread poll of own h word: (seq<<32)|f32bits
      const unsigned tgt = (unsigned)t;
      unsigned long long pk =
          __hip_atomic_load(&hbuf[tid], __ATOMIC_RELAXED, __HIP_MEMORY_SCOPE_AGENT);
      int guard = 0;
      while ((unsigned)(pk >> 32) < tgt && ++guard < 5000000) {
        __builtin_amdgcn_s_sleep(1);
        pk = __hip_atomic_load(&hbuf[tid], __ATOMIC_RELAXED, __HIP_MEMORY_SCOPE_AGENT);
      }
      float hv = __uint_as_float((unsigned)pk);
      hs[tid] = hv;
      hbf[tid] = (__bf16)hv;
      __syncthreads();  // B1
    }

    // stage s = tanh(A + h) as bf16 (rows >= nr stay zero)
    if (prow < nr) {
      const float* hp = &hs[pcol];
      v8bf sv;
      sv[0] = (__bf16)tanh_fast(a40.x + hp[0]);
      sv[1] = (__bf16)tanh_fast(a40.y + hp[1]);
      sv[2] = (__bf16)tanh_fast(a40.z + hp[2]);
      sv[3] = (__bf16)tanh_fast(a40.w + hp[3]);
      sv[4] = (__bf16)tanh_fast(a41.x + hp[4]);
      sv[5] = (__bf16)tanh_fast(a41.y + hp[5]);
      sv[6] = (__bf16)tanh_fast(a41.z + hp[6]);
      sv[7] = (__bf16)tanh_fast(a41.w + hp[7]);
      *(v8bf*)&Ss[prow][pcol] = sv;
    }
    __syncthreads();  // B2

    // logits = s @ W2^T + b2 (rows 0..7 valid)
    v4f acc[4];
    #pragma unroll
    for (int ntl = 0; ntl < 4; ntl++) acc[ntl] = (v4f){0.f, 0.f, 0.f, 0.f};
    #pragma unroll
    for (int k = 0; k < 8; k++) {
      const v8bf av = *(const v8bf*)&Ss[l15][k * 32 + quad * 8];
      #pragma unroll
      for (int ntl = 0; ntl < 4; ntl++)
        acc[ntl] = __builtin_amdgcn_mfma_f32_16x16x32_bf16(av, BW2[ntl][k], acc[ntl], 0, 0, 0);
    }
    if (quad < 2) {
      #pragma unroll
      for (int ntl = 0; ntl < 4; ntl++) {
        const int col = wv * 64 + ntl * 16 + l15;
        const float bb = b2s[col];
        #pragma unroll
        for (int reg = 0; reg < 4; reg++)
          Wt[quad * 4 + reg][col] = acc[ntl][reg] + bb;
      }
    }
    __syncthreads();  // B3

    // softmax (row = prow, 8 cols each, reduce across the 32-lane row group)
    // + ctx products into cxp (invalid rows stay zero)
    if (prow < nr) {
      float x[8];
      *(float4*)&x[0] = *(const float4*)&Wt[prow][pcol];
      *(float4*)&x[4] = *(const float4*)&Wt[prow][pcol + 4];
      float m = x[0];
      #pragma unroll
      for (int i = 1; i < 8; i++) m = fmaxf(m, x[i]);
      #pragma unroll
      for (int off = 16; off; off >>= 1) m = fmaxf(m, __shfl_xor(m, off, 64));
      float e[8], sm = 0.f;
      #pragma unroll
      for (int i = 0; i < 8; i++) { e[i] = __expf(x[i] - m); sm += e[i]; }
      #pragma unroll
      for (int off = 16; off; off >>= 1) sm += __shfl_xor(sm, off, 64);
      const float inv = __builtin_amdgcn_rcpf(sm);
      cxp[prow][pcol + 0] = e[0] * inv * v40.x;
      cxp[prow][pcol + 1] = e[1] * inv * v40.y;
      cxp[prow][pcol + 2] = e[2] * inv * v40.z;
      cxp[prow][pcol + 3] = e[3] * inv * v40.w;
      cxp[prow][pcol + 4] = e[4] * inv * v41.x;
      cxp[prow][pcol + 5] = e[5] * inv * v41.y;
      cxp[prow][pcol + 6] = e[6] * inv * v41.z;
      cxp[prow][pcol + 7] = e[7] * inv * v41.w;
    }
    __syncthreads();  // B5

    // channel sum of my WG's rows -> bf16 pack -> publish u64 (seq | 2×bf16)
    float cp = 0.f;
    #pragma unroll
    for (int r = 0; r < 8; r++) cp += cxp[r][tid];
    float cpo = __shfl_xor(cp, 1, 64);
    unsigned word = 0u;
    if ((tid & 1) == 0) {
      union { __bf16 b; unsigned short s; } lo, hi;
      lo.b = (__bf16)cp; hi.b = (__bf16)cpo;
      word = ((unsigned)hi.s << 16) | (unsigned)lo.s;
      unsigned long long pk =
          ((unsigned long long)(unsigned)(t + 1) << 32) | (unsigned long long)word;
      __hip_atomic_store(&cpub[w * 128 + (tid >> 1)], pk, __ATOMIC_RELAXED, __HIP_MEMORY_SCOPE_AGENT);
      cpl[tid >> 1] = word;  // own partial also via LDS (skip the IF$ round trip)
    }
    __syncthreads();  // B6 (cheap: makes cpl visible WG-locally)

    // round-0 remote gather issue — flies during the Whh MFMA chain below
    unsigned long long g[8][4];
    const unsigned ctgt = (unsigned)(t + 1);
    const bool remote = (l15 < NWG) && (l15 != w);
    if (remote) {
      const unsigned long long* src = cpub + l15 * 128 + quad * 4;
      #pragma unroll
      for (int k = 0; k < 8; k++)
        #pragma unroll
        for (int q2 = 0; q2 < 4; q2++)
          g[k][q2] = __hip_atomic_load(&src[k * 16 + q2], __ATOMIC_RELAXED, __HIP_MEMORY_SCOPE_AGENT);
    }

    // h @ Whh^T chain (h known since step top) — overlaps the gather RT
    v4f gacc[2];
    gacc[0] = (v4f){0.f, 0.f, 0.f, 0.f};
    gacc[1] = (v4f){0.f, 0.f, 0.f, 0.f};
    #pragma unroll
    for (int k = 0; k < 8; k++) {
      v8bf hf;
      #pragma unroll
      for (int z = 0; z < 8; z++) hf[z] = (__bf16)0.f;
      if (l15 == 0) hf = *(const v8bf*)&hbf[k * 32 + quad * 8];
      gacc[0] = __builtin_amdgcn_mfma_f32_16x16x32_bf16(hf, BHH[0][k], gacc[0], 0, 0, 0);
      gacc[1] = __builtin_amdgcn_mfma_f32_16x16x32_bf16(hf, BHH[1][k], gacc[1], 0, 0, 0);
    }

    // verify round-0 seqs; re-poll only if stale
    {
      bool ok = true;
      if (remote) {
        #pragma unroll
        for (int k = 0; k < 8; k++)
          #pragma unroll
          for (int q2 = 0; q2 < 4; q2++)
            ok &= ((unsigned)(g[k][q2] >> 32) >= ctgt);
      }
      if (!__all(ok)) {
        int guard = 0;
        while (true) {
          __builtin_amdgcn_s_sleep(1);
          ok = true;
          if (remote) {
            const unsigned long long* src = cpub + l15 * 128 + quad * 4;
            #pragma unroll
            for (int k = 0; k < 8; k++)
              #pragma unroll
              for (int q2 = 0; q2 < 4; q2++) {
                g[k][q2] = __hip_atomic_load(&src[k * 16 + q2], __ATOMIC_RELAXED, __HIP_MEMORY_SCOPE_AGENT);
                ok &= ((unsigned)(g[k][q2] >> 32) >= ctgt);
              }
          }
          if (__all(ok) || ++guard > 5000000) break;
        }
      }
    }

    // P rows (bf16 ctx partials) directly as MFMA A-frags; accumulate
    #pragma unroll
    for (int k = 0; k < 8; k++) {
      union { unsigned u[4]; v8bf v; } pf;
      if (remote) {
        pf.u[0] = (unsigned)g[k][0]; pf.u[1] = (unsigned)g[k][1];
        pf.u[2] = (unsigned)g[k][2]; pf.u[3] = (unsigned)g[k][3];
      } else if (l15 == w) {
        pf.u[0] = cpl[k * 16 + quad * 4 + 0];
        pf.u[1] = cpl[k * 16 + quad * 4 + 1];
        pf.u[2] = cpl[k * 16 + quad * 4 + 2];
        pf.u[3] = cpl[k * 16 + quad * 4 + 3];
      } else {
        pf.u[0] = pf.u[1] = pf.u[2] = pf.u[3] = 0u;
      }
      gacc[0] = __builtin_amdgcn_mfma_f32_16x16x32_bf16(pf.v, BIH[0][k], gacc[0], 0, 0, 0);
      gacc[1] = __builtin_amdgcn_mfma_f32_16x16x32_bf16(pf.v, BIH[1][k], gacc[1], 0, 0, 0);
    }
    // reduce over P rows (D rows = quad*4+reg) -> per-col gate pre-activation
    #pragma unroll
    for (int nt = 0; nt < 2; nt++) {
      float tot = gacc[nt][0] + gacc[nt][1] + gacc[nt][2] + gacc[nt][3];
      tot += __shfl_xor(tot, 16, 64);
      tot += __shfl_xor(tot, 32, 64);
      if (lane < 16) gb[wv][nt * 16 + lane] = tot;
    }
    __syncthreads();  // B7

    // cell update for my 32 dims; publish h slice as (seq | f32bits)
    if (tid < 32) {
      float gi = gb[0][tid] + cbias[0];
      float gf = gb[1][tid] + cbias[1];
      float gg = gb[2][tid] + cbias[2];
      float go = gb[3][tid] + cbias[3];
      float si = sigm_fast(gi);
      float sf = sigm_fast(gf);
      float so = sigm_fast(go);
      creg = sf * creg + si * tanh_fast(gg);
      float hn = so * tanh_fast(creg);
      unsigned long long pk = ((unsigned long long)(unsigned)(t + 1) << 32) |
                              (unsigned long long)__float_as_uint(hn);
      __hip_atomic_store(&hbuf[32 * w + tid], pk, __ATOMIC_RELAXED, __HIP_MEMORY_SCOPE_AGENT);
    }
    // no drain barrier, no flag: the u64 word is self-announcing
  }

  // q = h_T @ q_w^T + q_b
  if (w == 0) {
    const unsigned tgt = (unsigned)T_FRAMES;
    unsigned long long pk =
        __hip_atomic_load(&hbuf[tid], __ATOMIC_RELAXED, __HIP_MEMORY_SCOPE_AGENT);
    int guard = 0;
    while ((unsigned)(pk >> 32) < tgt && ++guard < 5000000) {
      __builtin_amdgcn_s_sleep(1);
      pk = __hip_atomic_load(&hbuf[tid], __ATOMIC_RELAXED, __HIP_MEMORY_SCOPE_AGENT);
    }
    hs[tid] = __uint_as_float((unsigned)pk);
    __syncthreads();
    if (tid < NA) {
      float acc = qb[tid];
      for (int k = 0; k < HID; k++) acc += hs[k] * qw[tid * HID + k];
      out[tid] = acc;
    }
  }
}

extern "C" void kernel_launch(void* const* d_in, const int* in_sizes, int n_in,
                              void* d_out, int out_size, void* d_ws, size_t ws_size,
                              hipStream_t stream) {
  const float* frames = (const float*)d_in[0];
  const float* c1w = (const float*)d_in[1];
  const float* c1b = (const float*)d_in[2];
  const float* c2w = (const float*)d_in[3];
  const float* c2b = (const float*)d_in[4];
  const float* c3w = (const float*)d_in[5];
  const float* c3b = (const float*)d_in[6];
  const float* aw1 = (const float*)d_in[7];
  const float* ab1 = (const float*)d_in[8];
  const float* aw2 = (const float*)d_in[9];
  const float* ab2 = (const float*)d_in[10];
  const float* wih = (const float*)d_in[11];
  const float* whh = (const float*)d_in[12];
  const float* bih = (const float*)d_in[13];
  const float* bhh = (const float*)d_in[14];
  const float* qw  = (const float*)d_in[15];
  const float* qb  = (const float*)d_in[16];

  char* ws = (char*)d_ws;
  float*  fm1   = (float*)(ws + OFF_FM1);
  float*  A     = (float*)(ws + OFF_FM1);   // alias: fm1 dead after conv2
  float*  fm2   = (float*)(ws + OFF_FM2);
  float*  vecs  = (float*)(ws + OFF_VECS);
  __bf16* w2b   = (__bf16*)(ws + OFF_W2B);
  __bf16* wihb  = (__bf16*)(ws + OFF_WIHB);
  __bf16* whhb  = (__bf16*)(ws + OFF_WHHB);
  float*  w1t   = (float*)(ws + OFF_W1T);
  unsigned long long* hbuf = (unsigned long long*)(ws + OFF_HBUF);  // aliases fm2
  unsigned long long* cpub = (unsigned long long*)(ws + OFF_CPUB);

  prep_weights<<<256, 256, 0, stream>>>(aw2, wih, whh, aw1, w2b, wihb, whhb, w1t);
  conv1_k<<<102400, 256, 0, stream>>>(frames, c1w, c1b, fm1);
  conv2_k<<<T_FRAMES, 256, 0, stream>>>(fm1, c2w, c2b, fm2);
  conv3_k<<<T_FRAMES, 256, 0, stream>>>(fm2, c3w, c3b, vecs);
  aprep_k<<<T_FRAMES, 256, 0, stream>>>(vecs, w1t, ab1, A);
  init_comm<<<4, 256, 0, stream>>>(hbuf, cpub);  // after conv3: comm aliases fm2
  scan_k<<<57, 256, 0, stream>>>(A, vecs, w2b, wihb, whhb, ab2, bih, bhh, qw, qb,
                                 hbuf, cpub, (float*)d_out);
}

// Round 2
// 15286.983 us; speedup vs baseline: 1.1366x; 1.1366x over previous
//
#include <hip/hip_runtime.h>
#include <hip/hip_bf16.h>
#include <math.h>

// DARQN: conv×3 -> per-step additive attention + LSTM scan (T=2048) -> q head.
// R4: R2 structure + seq-embedded u64 comm words done right.
//  - h broadcast: u64 = (seq<<32)|f32bits; per-thread poll of own word; the
//    detecting load IS the data load (saves the post-detect h-fetch RT).
//  - ctx partials: u64 = (seq<<32)|2×bf16; ONE uniform poll-gather loop after
//    the Whh MFMA chain (no speculative round-0, no divergent re-poll): each
//    iteration loads the remote set pipelined and checks seqs; the successful
//    iteration already holds the MFMA A-fragments (saves the gather RT).
//  - own-WG partial via LDS (cpl), no IF$ round trip for it.
//  - no flag arrays, no release fences, no drain barriers; 6 barriers/step.
//  - rcp-based tanh/sigmoid/softmax-inv.

#define T_FRAMES 2048
#define NI 49
#define HID 256
#define NA 18
#define NWG 8

typedef __bf16 v8bf __attribute__((ext_vector_type(8)));
typedef float v4f __attribute__((ext_vector_type(4)));

// ---------------- workspace layout (bytes) ----------------
static constexpr size_t OFF_FM1   = 0;                  // fm1 [2048,32,20,20] f32; reused for A [2048,49,256] f32
static constexpr size_t OFF_FM2   = 104857600;          // fm2 [2048,64,9,9] f32; reused for comm block
static constexpr size_t OFF_VECS  = 147324928;          // vecs [2048,49,256] f32
static constexpr size_t OFF_W2B   = 250085376;          // bf16 256*256
static constexpr size_t OFF_WIHB  = OFF_W2B  + 131072;  // bf16 1024*256
static constexpr size_t OFF_WHHB  = OFF_WIHB + 524288;  // bf16 1024*256
static constexpr size_t OFF_W1T   = OFF_WHHB + 524288;  // f32 256*256
// comm block aliases fm2 region (valid after conv3 consumed fm2):
static constexpr size_t OFF_HBUF  = OFF_FM2;            // u64[256]  (seq|f32)
static constexpr size_t OFF_CPUB  = OFF_FM2 + 2048;     // u64[8*128] (seq | 2×bf16)

// ---------------- weight prep ----------------
__global__ void prep_weights(const float* __restrict__ w2, const float* __restrict__ wih,
                             const float* __restrict__ whh, const float* __restrict__ w1,
                             __bf16* w2b, __bf16* wihb, __bf16* whhb, float* w1t) {
  int idx = blockIdx.x * 256 + threadIdx.x;
  int stride = gridDim.x * 256;
  for (int i = idx; i < 65536; i += stride) w2b[i] = (__bf16)w2[i];
  for (int i = idx; i < 262144; i += stride) wihb[i] = (__bf16)wih[i];
  for (int i = idx; i < 262144; i += stride) whhb[i] = (__bf16)whh[i];
  for (int i = idx; i < 65536; i += stride) {
    int r = i >> 8, c = i & 255;
    w1t[c * 256 + r] = w1[i];
  }
}

// ---------------- conv1: [T,1,84,84] -> [T,32,20,20], k8 s4 ----------------
__global__ void conv1_k(const float* __restrict__ x, const float* __restrict__ w,
                        const float* __restrict__ b, float* __restrict__ y) {
  int idx = blockIdx.x * 256 + threadIdx.x;
  if (idx >= T_FRAMES * 32 * 20 * 20) return;
  int xx = idx % 20, yy = (idx / 20) % 20, o = (idx / 400) % 32, t = idx / 12800;
  const float* xp = x + t * 7056 + yy * 4 * 84 + xx * 4;
  const float* wp = w + o * 64;
  float acc = b[o];
  #pragma unroll
  for (int ky = 0; ky < 8; ky++)
    #pragma unroll
    for (int kx = 0; kx < 8; kx++)
      acc += xp[ky * 84 + kx] * wp[ky * 8 + kx];
  y[idx] = fmaxf(acc, 0.f);
}

// ---------------- conv2: [T,32,20,20] -> [T,64,9,9], k4 s2 ----------------
__global__ __launch_bounds__(256) void conv2_k(const float* __restrict__ fm1, const float* __restrict__ w,
                                               const float* __restrict__ b, float* __restrict__ fm2) {
  __shared__ float xs[32 * 400];
  int t = blockIdx.x, tid = threadIdx.x;
  for (int i = tid; i < 12800; i += 256) xs[i] = fm1[t * 12800 + i];
  __syncthreads();
  int o = tid >> 2, q = tid & 3;
  int p0 = q * 21, p1 = (p0 + 21 < 81) ? p0 + 21 : 81;
  int ob[21];
  #pragma unroll
  for (int i2 = 0; i2 < 21; i2++) {
    int p = p0 + i2; if (p > 80) p = 80;
    int yy = p / 9, xx2 = p - yy * 9;
    ob[i2] = yy * 40 + xx2 * 2;
  }
  float acc[21];
  #pragma unroll
  for (int i2 = 0; i2 < 21; i2++) acc[i2] = 0.f;
  for (int c = 0; c < 32; c++) {
    int cbase = c * 400;
    for (int ky = 0; ky < 4; ky++)
      for (int kx = 0; kx < 4; kx++) {
        float wgt = w[((o * 32 + c) * 4 + ky) * 4 + kx];
        int kyo = ky * 20 + kx;
        #pragma unroll
        for (int i2 = 0; i2 < 21; i2++)
          acc[i2] += wgt * xs[cbase + ob[i2] + kyo];
      }
  }
  float bo = b[o];
  #pragma unroll
  for (int i2 = 0; i2 < 21; i2++) {
    int p = p0 + i2;
    if (p < p1) fm2[t * 5184 + o * 81 + p] = fmaxf(acc[i2] + bo, 0.f);
  }
}

// ---------------- conv3: [T,64,9,9] -> vecs [T,49,256], k3 s1 ----------------
__global__ __launch_bounds__(256) void conv3_k(const float* __restrict__ fm2, const float* __restrict__ w,
                                               const float* __restrict__ b, float* __restrict__ vecs) {
  __shared__ float xs[64 * 81];
  __shared__ float ws4[256][37];
  int t = blockIdx.x, tid = threadIdx.x;
  for (int i = tid; i < 64 * 81; i += 256) xs[i] = fm2[t * 5184 + i];
  float acc[49];
  #pragma unroll
  for (int i = 0; i < 49; i++) acc[i] = 0.f;
  for (int c0 = 0; c0 < 64; c0 += 4) {
    __syncthreads();
    for (int i = tid; i < 256 * 36; i += 256) {
      int oo = i / 36, j = i - oo * 36;
      ws4[oo][j] = w[oo * 576 + c0 * 9 + j];
    }
    __syncthreads();
    for (int cc = 0; cc < 4; cc++)
      for (int ky = 0; ky < 3; ky++)
        for (int kx = 0; kx < 3; kx++) {
          float wgt = ws4[tid][cc * 9 + ky * 3 + kx];
          const float* xp = &xs[(c0 + cc) * 81 + ky * 9 + kx];
          #pragma unroll
          for (int yy = 0; yy < 7; yy++)
            #pragma unroll
            for (int xx = 0; xx < 7; xx++)
              acc[yy * 7 + xx] += wgt * xp[yy * 9 + xx];
        }
  }
  float bo = b[tid];
  for (int i = 0; i < 49; i++)
    vecs[(t * 49 + i) * 256 + tid] = fmaxf(acc[i] + bo, 0.f);
}

// ---------------- A[t,i,:] = vecs[t,i,:] @ W1^T + b1 ----------------
__global__ __launch_bounds__(256) void aprep_k(const float* __restrict__ vecs, const float* __restrict__ w1t,
                                               const float* __restrict__ b1, float* __restrict__ A) {
  __shared__ float vs[49][256];
  int t = blockIdx.x, tid = threadIdx.x;
  for (int i = tid; i < 49 * 256; i += 256) vs[i >> 8][i & 255] = vecs[t * 12544 + i];
  __syncthreads();
  float acc[49];
  #pragma unroll
  for (int i = 0; i < 49; i++) acc[i] = 0.f;
  for (int k = 0; k < 256; k++) {
    float wgt = w1t[k * 256 + tid];
    #pragma unroll
    for (int i = 0; i < 49; i++) acc[i] += vs[i][k] * wgt;
  }
  float bb = b1[tid];
  for (int i = 0; i < 49; i++) A[(t * 49 + i) * 256 + tid] = acc[i] + bb;
}

// ---------------- init comm words (after conv3: aliases fm2) ----------------
__global__ void init_comm(unsigned long long* hbuf, unsigned long long* cpub) {
  int idx = blockIdx.x * 256 + threadIdx.x;
  if (idx < 256) hbuf[idx] = 0ull;
  if (idx < NWG * 128) cpub[idx] = 0ull;
}

__device__ __forceinline__ float tanh_fast(float x) {
  float e = __expf(2.f * x);
  return 1.f - 2.f * __builtin_amdgcn_rcpf(e + 1.f);
}
__device__ __forceinline__ float sigm_fast(float x) {
  return __builtin_amdgcn_rcpf(1.f + __expf(-x));
}

// ---------------- sequential scan: 8 persistent WGs, seq-embedded u64 comm ----------------
__global__ __launch_bounds__(256, 1) void scan_k(
    const float* __restrict__ A, const float* __restrict__ vecs,
    const __bf16* __restrict__ w2b, const __bf16* __restrict__ wihb, const __bf16* __restrict__ whhb,
    const float* __restrict__ b2g, const float* __restrict__ bihg, const float* __restrict__ bhhg,
    const float* __restrict__ qw, const float* __restrict__ qb,
    unsigned long long* hbuf, unsigned long long* cpub, float* out) {
  const int w = blockIdx.x;     // worker 0..7

  __shared__ __bf16 Ss[16][264];   // row byte-stride 528 (16B-aligned)
  __shared__ float hs[HID];
  __shared__ __bf16 hbf[HID];
  __shared__ float Wt[8][HID];     // logits / softmax rows
  __shared__ float cxp[8][HID];    // per-row ctx products
  __shared__ float b2s[HID];
  __shared__ float gb[4][32];
  __shared__ unsigned cpl[128];    // own-WG ctx partial (packed bf16 pairs)

  const int tid = threadIdx.x;
  const int lane = tid & 63;
  const int wv = tid >> 6;          // wave 0..3 (= LSTM gate id)
  const int quad = lane >> 4;
  const int l15 = lane & 15;
  const int r0 = 6 * w;                       // attention rows [r0, r0+nr)
  const int nr = (w < 7) ? 6 : 7;             // 7*6 + 7 = 49
  const int prow = tid >> 5;        // 0..7: staging row
  const int pcol = (tid & 31) * 8;  // 8 contiguous cols

  for (int i = tid; i < 16 * 264; i += 256) (&Ss[0][0])[i] = (__bf16)0.f;
  for (int i = tid; i < 8 * HID; i += 256) (&cxp[0][0])[i] = 0.f;
  b2s[tid] = b2g[tid];
  hs[tid] = 0.f;
  hbf[tid] = (__bf16)0.f;
  float cbias[4];
  if (tid < 32) {
    #pragma unroll
    for (int g = 0; g < 4; g++) {
      int row = 256 * g + 32 * w + tid;
      cbias[g] = bihg[row] + bhhg[row];
    }
  }
  float creg = 0.f;  // cell state, tid<32 owns dim 32*w+tid

  // ---- register-resident MFMA B-fragments ----
  v8bf BW2[4][8];  // attention: wave wv owns logit cols wv*64 + ntl*16 + l15
  #pragma unroll
  for (int ntl = 0; ntl < 4; ntl++) {
    const int row = wv * 64 + ntl * 16 + l15;
    #pragma unroll
    for (int k = 0; k < 8; k++)
      BW2[ntl][k] = *(const v8bf*)(w2b + row * 256 + k * 32 + quad * 8);
  }
  v8bf BIH[2][8], BHH[2][8];  // LSTM: gate wv, dims 32*w + nt*16 + l15
  #pragma unroll
  for (int nt = 0; nt < 2; nt++) {
    const int row = 256 * wv + 32 * w + nt * 16 + l15;
    #pragma unroll
    for (int k = 0; k < 8; k++) {
      BIH[nt][k] = *(const v8bf*)(wihb + row * 256 + k * 32 + quad * 8);
      BHH[nt][k] = *(const v8bf*)(whhb + row * 256 + k * 32 + quad * 8);
    }
  }
  __syncthreads();

  for (int t = 0; t < T_FRAMES; t++) {
    // issue this step's A/vecs loads (fly during the h wait)
    int rr = r0 + prow; if (rr > 48) rr = 48;
    const float* Ap = A + ((long)t * NI + rr) * HID + pcol;
    const float* Vp = vecs + ((long)t * NI + rr) * HID + pcol;
    const float4 a40 = *(const float4*)(Ap);
    const float4 a41 = *(const float4*)(Ap + 4);
    const float4 v40 = *(const float4*)(Vp);
    const float4 v41 = *(const float4*)(Vp + 4);

    if (t > 0) {  // per-thread poll of own h word: (seq<<32)|f32bits
      const unsigned tgt = (unsigned)t;
      unsigned long long pk =
          __hip_atomic_load(&hbuf[tid], __ATOMIC_RELAXED, __HIP_MEMORY_SCOPE_AGENT);
      int guard = 0;
      while ((unsigned)(pk >> 32) < tgt && ++guard < 5000000) {
        __builtin_amdgcn_s_sleep(1);
        pk = __hip_atomic_load(&hbuf[tid], __ATOMIC_RELAXED, __HIP_MEMORY_SCOPE_AGENT);
      }
      float hv = __uint_as_float((unsigned)pk);
      hs[tid] = hv;
      hbf[tid] = (__bf16)hv;
      __syncthreads();  // B1
    }

    // stage s = tanh(A + h) as bf16 (rows >= nr stay zero)
    if (prow < nr) {
      const float* hp = &hs[pcol];
      v8bf sv;
      sv[0] = (__bf16)tanh_fast(a40.x + hp[0]);
      sv[1] = (__bf16)tanh_fast(a40.y + hp[1]);
      sv[2] = (__bf16)tanh_fast(a40.z + hp[2]);
      sv[3] = (__bf16)tanh_fast(a40.w + hp[3]);
      sv[4] = (__bf16)tanh_fast(a41.x + hp[4]);
      sv[5] = (__bf16)tanh_fast(a41.y + hp[5]);
      sv[6] = (__bf16)tanh_fast(a41.z + hp[6]);
      sv[7] = (__bf16)tanh_fast(a41.w + hp[7]);
      *(v8bf*)&Ss[prow][pcol] = sv;
    }
    __syncthreads();  // B2

    // logits = s @ W2^T + b2 (rows 0..7 valid)
    v4f acc[4];
    #pragma unroll
    for (int ntl = 0; ntl < 4; ntl++) acc[ntl] = (v4f){0.f, 0.f, 0.f, 0.f};
    #pragma unroll
    for (int k = 0; k < 8; k++) {
      const v8bf av = *(const v8bf*)&Ss[l15][k * 32 + quad * 8];
      #pragma unroll
      for (int ntl = 0; ntl < 4; ntl++)
        acc[ntl] = __builtin_amdgcn_mfma_f32_16x16x32_bf16(av, BW2[ntl][k], acc[ntl], 0, 0, 0);
    }
    if (quad < 2) {
      #pragma unroll
      for (int ntl = 0; ntl < 4; ntl++) {
        const int col = wv * 64 + ntl * 16 + l15;
        const float bb = b2s[col];
        #pragma unroll
        for (int reg = 0; reg < 4; reg++)
          Wt[quad * 4 + reg][col] = acc[ntl][reg] + bb;
      }
    }
    __syncthreads();  // B3

    // softmax (row = prow, 8 cols each, reduce across the 32-lane row group)
    // + ctx products into cxp (invalid rows stay zero)
    if (prow < nr) {
      float x[8];
      *(float4*)&x[0] = *(const float4*)&Wt[prow][pcol];
      *(float4*)&x[4] = *(const float4*)&Wt[prow][pcol + 4];
      float m = x[0];
      #pragma unroll
      for (int i = 1; i < 8; i++) m = fmaxf(m, x[i]);
      #pragma unroll
      for (int off = 16; off; off >>= 1) m = fmaxf(m, __shfl_xor(m, off, 64));
      float e[8], sm = 0.f;
      #pragma unroll
      for (int i = 0; i < 8; i++) { e[i] = __expf(x[i] - m); sm += e[i]; }
      #pragma unroll
      for (int off = 16; off; off >>= 1) sm += __shfl_xor(sm, off, 64);
      const float inv = __builtin_amdgcn_rcpf(sm);
      cxp[prow][pcol + 0] = e[0] * inv * v40.x;
      cxp[prow][pcol + 1] = e[1] * inv * v40.y;
      cxp[prow][pcol + 2] = e[2] * inv * v40.z;
      cxp[prow][pcol + 3] = e[3] * inv * v40.w;
      cxp[prow][pcol + 4] = e[4] * inv * v41.x;
      cxp[prow][pcol + 5] = e[5] * inv * v41.y;
      cxp[prow][pcol + 6] = e[6] * inv * v41.z;
      cxp[prow][pcol + 7] = e[7] * inv * v41.w;
    }
    __syncthreads();  // B5

    // channel sum of my WG's rows -> bf16 pack -> publish u64 (seq | 2×bf16)
    float cp = 0.f;
    #pragma unroll
    for (int r = 0; r < 8; r++) cp += cxp[r][tid];
    float cpo = __shfl_xor(cp, 1, 64);
    if ((tid & 1) == 0) {
      union { __bf16 b; unsigned short s; } lo, hi;
      lo.b = (__bf16)cp; hi.b = (__bf16)cpo;
      unsigned word = ((unsigned)hi.s << 16) | (unsigned)lo.s;
      unsigned long long pk =
          ((unsigned long long)(unsigned)(t + 1) << 32) | (unsigned long long)word;
      __hip_atomic_store(&cpub[w * 128 + (tid >> 1)], pk, __ATOMIC_RELAXED, __HIP_MEMORY_SCOPE_AGENT);
      cpl[tid >> 1] = word;  // own partial via LDS (skip the IF$ round trip)
    }
    __syncthreads();  // B6 (makes cpl visible WG-locally; also fences cxp reuse)

    // h @ Whh^T chain (h known since step top) — runs while remote publishes land
    v4f gacc[2];
    gacc[0] = (v4f){0.f, 0.f, 0.f, 0.f};
    gacc[1] = (v4f){0.f, 0.f, 0.f, 0.f};
    #pragma unroll
    for (int k = 0; k < 8; k++) {
      v8bf hf;
      #pragma unroll
      for (int z = 0; z < 8; z++) hf[z] = (__bf16)0.f;
      if (l15 == 0) hf = *(const v8bf*)&hbf[k * 32 + quad * 8];
      gacc[0] = __builtin_amdgcn_mfma_f32_16x16x32_bf16(hf, BHH[0][k], gacc[0], 0, 0, 0);
      gacc[1] = __builtin_amdgcn_mfma_f32_16x16x32_bf16(hf, BHH[1][k], gacc[1], 0, 0, 0);
    }

    // uniform poll-gather of remote ctx partials (last iteration == the data)
    unsigned long long g[8][4];
    const unsigned ctgt = (unsigned)(t + 1);
    const bool remote = (l15 < NWG) && (l15 != w);
    {
      int guard = 0;
      while (true) {
        bool ok = true;
        if (remote) {
          const unsigned long long* src = cpub + l15 * 128 + quad * 4;
          #pragma unroll
          for (int k = 0; k < 8; k++)
            #pragma unroll
            for (int q2 = 0; q2 < 4; q2++) {
              g[k][q2] = __hip_atomic_load(&src[k * 16 + q2], __ATOMIC_RELAXED, __HIP_MEMORY_SCOPE_AGENT);
              ok &= ((unsigned)(g[k][q2] >> 32) >= ctgt);
            }
        }
        if (__all(ok) || ++guard > 5000000) break;
        __builtin_amdgcn_s_sleep(1);
      }
    }

    // P rows (bf16 ctx partials) directly as MFMA A-frags; accumulate
    #pragma unroll
    for (int k = 0; k < 8; k++) {
      union { unsigned u[4]; v8bf v; } pf;
      if (remote) {
        pf.u[0] = (unsigned)g[k][0]; pf.u[1] = (unsigned)g[k][1];
        pf.u[2] = (unsigned)g[k][2]; pf.u[3] = (unsigned)g[k][3];
      } else if (l15 == w) {
        pf.u[0] = cpl[k * 16 + quad * 4 + 0];
        pf.u[1] = cpl[k * 16 + quad * 4 + 1];
        pf.u[2] = cpl[k * 16 + quad * 4 + 2];
        pf.u[3] = cpl[k * 16 + quad * 4 + 3];
      } else {
        pf.u[0] = pf.u[1] = pf.u[2] = pf.u[3] = 0u;
      }
      gacc[0] = __builtin_amdgcn_mfma_f32_16x16x32_bf16(pf.v, BIH[0][k], gacc[0], 0, 0, 0);
      gacc[1] = __builtin_amdgcn_mfma_f32_16x16x32_bf16(pf.v, BIH[1][k], gacc[1], 0, 0, 0);
    }
    // reduce over P rows (D rows = quad*4+reg) -> per-col gate pre-activation
    #pragma unroll
    for (int nt = 0; nt < 2; nt++) {
      float tot = gacc[nt][0] + gacc[nt][1] + gacc[nt][2] + gacc[nt][3];
      tot += __shfl_xor(tot, 16, 64);
      tot += __shfl_xor(tot, 32, 64);
      if (lane < 16) gb[wv][nt * 16 + lane] = tot;
    }
    __syncthreads();  // B7

    // cell update for my 32 dims; publish h slice as (seq | f32bits)
    if (tid < 32) {
      float gi = gb[0][tid] + cbias[0];
      float gf = gb[1][tid] + cbias[1];
      float gg = gb[2][tid] + cbias[2];
      float go = gb[3][tid] + cbias[3];
      float si = sigm_fast(gi);
      float sf = sigm_fast(gf);
      float so = sigm_fast(go);
      creg = sf * creg + si * tanh_fast(gg);
      float hn = so * tanh_fast(creg);
      unsigned long long pk = ((unsigned long long)(unsigned)(t + 1) << 32) |
                              (unsigned long long)__float_as_uint(hn);
      __hip_atomic_store(&hbuf[32 * w + tid], pk, __ATOMIC_RELAXED, __HIP_MEMORY_SCOPE_AGENT);
    }
    // no drain barrier, no flag: the u64 word is self-announcing
  }

  // q = h_T @ q_w^T + q_b
  if (w == 0) {
    const unsigned tgt = (unsigned)T_FRAMES;
    unsigned long long pk =
        __hip_atomic_load(&hbuf[tid], __ATOMIC_RELAXED, __HIP_MEMORY_SCOPE_AGENT);
    int guard = 0;
    while ((unsigned)(pk >> 32) < tgt && ++guard < 5000000) {
      __builtin_amdgcn_s_sleep(1);
      pk = __hip_atomic_load(&hbuf[tid], __ATOMIC_RELAXED, __HIP_MEMORY_SCOPE_AGENT);
    }
    hs[tid] = __uint_as_float((unsigned)pk);
    __syncthreads();
    if (tid < NA) {
      float acc = qb[tid];
      for (int k = 0; k < HID; k++) acc += hs[k] * qw[tid * HID + k];
      out[tid] = acc;
    }
  }
}

extern "C" void kernel_launch(void* const* d_in, const int* in_sizes, int n_in,
                              void* d_out, int out_size, void* d_ws, size_t ws_size,
                              hipStream_t stream) {
  const float* frames = (const float*)d_in[0];
  const float* c1w = (const float*)d_in[1];
  const float* c1b = (const float*)d_in[2];
  const float* c2w = (const float*)d_in[3];
  const float* c2b = (const float*)d_in[4];
  const float* c3w = (const float*)d_in[5];
  const float* c3b = (const float*)d_in[6];
  const float* aw1 = (const float*)d_in[7];
  const float* ab1 = (const float*)d_in[8];
  const float* aw2 = (const float*)d_in[9];
  const float* ab2 = (const float*)d_in[10];
  const float* wih = (const float*)d_in[11];
  const float* whh = (const float*)d_in[12];
  const float* bih = (const float*)d_in[13];
  const float* bhh = (const float*)d_in[14];
  const float* qw  = (const float*)d_in[15];
  const float* qb  = (const float*)d_in[16];

  char* ws = (char*)d_ws;
  float*  fm1   = (float*)(ws + OFF_FM1);
  float*  A     = (float*)(ws + OFF_FM1);   // alias: fm1 dead after conv2
  float*  fm2   = (float*)(ws + OFF_FM2);
  float*  vecs  = (float*)(ws + OFF_VECS);
  __bf16* w2b   = (__bf16*)(ws + OFF_W2B);
  __bf16* wihb  = (__bf16*)(ws + OFF_WIHB);
  __bf16* whhb  = (__bf16*)(ws + OFF_WHHB);
  float*  w1t   = (float*)(ws + OFF_W1T);
  unsigned long long* hbuf = (unsigned long long*)(ws + OFF_HBUF);  // aliases fm2
  unsigned long long* cpub = (unsigned long long*)(ws + OFF_CPUB);

  prep_weights<<<256, 256, 0, stream>>>(aw2, wih, whh, aw1, w2b, wihb, whhb, w1t);
  conv1_k<<<102400, 256, 0, stream>>>(frames, c1w, c1b, fm1);
  conv2_k<<<T_FRAMES, 256, 0, stream>>>(fm1, c2w, c2b, fm2);
  conv3_k<<<T_FRAMES, 256, 0, stream>>>(fm2, c3w, c3b, vecs);
  aprep_k<<<T_FRAMES, 256, 0, stream>>>(vecs, w1t, ab1, A);
  init_comm<<<4, 256, 0, stream>>>(hbuf, cpub);  // after conv3: comm aliases fm2
  scan_k<<<NWG, 256, 0, stream>>>(A, vecs, w2b, wihb, whhb, ab2, bih, bhh, qw, qb,
                                  hbuf, cpub, (float*)d_out);
}